// Round 1
// 518.853 us; speedup vs baseline: 1.1894x; 1.1894x over previous
//
#include <hip/hip_runtime.h>
#include <hip/hip_bf16.h>
#include <math.h>

#define B_   2
#define S_   2048
#define D_   2048
#define H_   16
#define HD_  128
#define ROT_ 32
#define M_   (B_*S_)    // 4096 tokens
#define N3_  (3*D_)     // 6144

static constexpr float SCALE_ = 0.08838834764831845f;  // 1/sqrt(128)

typedef __attribute__((ext_vector_type(4))) float  f32x4;
typedef __attribute__((ext_vector_type(8))) __bf16 bf16x8;

__device__ inline unsigned short f2bf(float f) {
    unsigned int u = __builtin_bit_cast(unsigned int, f);
    unsigned int r = (u + 0x7fffu + ((u >> 16) & 1u)) >> 16;
    return (unsigned short)r;
}
__device__ inline float bf2f(unsigned short h) {
    unsigned int u = ((unsigned int)h) << 16;
    return __builtin_bit_cast(float, u);
}

#define GLDS(g, l) __builtin_amdgcn_global_load_lds(                          \
    (const __attribute__((address_space(1))) void*)(g),                       \
    (__attribute__((address_space(3))) void*)(l), 16, 0, 0)

// ---------------------------------------------------------------- cast fp32 -> bf16
__global__ void cast_bf16_kernel(const float* __restrict__ src,
                                 unsigned short* __restrict__ dst, int n4) {
    int i = blockIdx.x * blockDim.x + threadIdx.x;
    if (i < n4) {
        float4 v = ((const float4*)src)[i];
        ushort4 o;
        o.x = f2bf(v.x); o.y = f2bf(v.y); o.z = f2bf(v.z); o.w = f2bf(v.w);
        ((ushort4*)dst)[i] = o;
    }
}

// ------------------------------------------- transpose+cast (conflict-free)
__global__ __launch_bounds__(256) void transpose_cast_kernel(
    const float* __restrict__ src, unsigned short* __restrict__ dst,
    int R, int ldS)
{
    __shared__ float tile[32][33];
    int c0 = blockIdx.x * 32, r0 = blockIdx.y * 32;
    int tx = threadIdx.x & 31, ty = threadIdx.x >> 5;  // ty 0..7
#pragma unroll
    for (int i = 0; i < 4; i++)
        tile[ty + i*8][tx] = src[(size_t)(r0 + ty + i*8) * ldS + c0 + tx];
    __syncthreads();
#pragma unroll
    for (int i = 0; i < 4; i++)
        dst[(size_t)(c0 + ty + i*8) * R + r0 + tx] = f2bf(tile[tx][ty + i*8]);
}

// ---------------------------------------------------------------- GEMM (B^T, GLDS both sides)
// (verified r6) C = A @ B + bias. A: M x K row-major (fp32->register cast if
// ABF16==0; bf16 GLDS if 1). BT: bf16 [n_local][K]. n0 = n_base + bx*128.
// MODE 0: fp32 C (+bias). MODE 1: qkv epilogue (bias+RoPE+head-split scatter).
template <int ABF16, int MODE>
__global__ __launch_bounds__(256) void gemm_bt2_kernel(
    const void* __restrict__ Aptr,
    const unsigned short* __restrict__ BT,
    const float* __restrict__ bias,
    void* __restrict__ out0,
    unsigned short* __restrict__ out1,
    unsigned short* __restrict__ out2,
    int Ndim, int K, int n_base)
{
    __shared__ unsigned short sA[128 * 32];
    __shared__ unsigned short sB[128 * 32];
    const int tid  = threadIdx.x;
    const int m0   = blockIdx.y * 128;
    const int nloc = blockIdx.x * 128;
    const int n0   = n_base + nloc;
    const int lane = tid & 63, wave = tid >> 6;
    const int wr = wave >> 1, wc = wave & 1;
    const int lrow = lane & 15, lk = (lane >> 4) * 8;

    f32x4 acc[4][4] = {};

    const unsigned short* Bg = BT + (size_t)(nloc + tid/4) * K + (tid & 3) * 8;

    for (int k0 = 0; k0 < K; k0 += 32) {
        if (ABF16) {
            const unsigned short* Ab = (const unsigned short*)Aptr;
#pragma unroll
            for (int c = 0; c < 2; c++)
                GLDS(Ab + (size_t)(m0 + c*64 + tid/4) * K + k0 + (tid & 3) * 8,
                     sA + c*2048 + tid*8);
        } else {
            const float* Af = (const float*)Aptr;
#pragma unroll
            for (int p = 0; p < 4; p++) {
                int row = p*32 + tid/8, col = (tid & 7) * 4;
                float4 v = *(const float4*)&Af[(size_t)(m0 + row) * K + k0 + col];
                ushort4 o;
                o.x = f2bf(v.x); o.y = f2bf(v.y); o.z = f2bf(v.z); o.w = f2bf(v.w);
                *(ushort4*)&sA[row*32 + col] = o;
            }
        }
#pragma unroll
        for (int c = 0; c < 2; c++)
            GLDS(Bg + (size_t)c*64*K + k0, sB + c*2048 + tid*8);
        __syncthreads();
        bf16x8 af[4], bfj[4];
#pragma unroll
        for (int i = 0; i < 4; i++)
            af[i]  = *(const bf16x8*)&sA[(wr*64 + i*16 + lrow)*32 + lk];
#pragma unroll
        for (int j = 0; j < 4; j++)
            bfj[j] = *(const bf16x8*)&sB[(wc*64 + j*16 + lrow)*32 + lk];
#pragma unroll
        for (int i = 0; i < 4; i++)
#pragma unroll
            for (int j = 0; j < 4; j++)
                acc[i][j] = __builtin_amdgcn_mfma_f32_16x16x32_bf16(af[i], bfj[j], acc[i][j], 0, 0, 0);
        __syncthreads();
    }

    if (MODE == 0) {
#pragma unroll
        for (int i = 0; i < 4; i++) {
#pragma unroll
            for (int j = 0; j < 4; j++) {
                int col = n0 + wc*64 + j*16 + lrow;
                float bv = bias[col];
#pragma unroll
                for (int r = 0; r < 4; r++) {
                    int row = m0 + wr*64 + i*16 + (lane >> 4)*4 + r;
                    ((float*)out0)[(size_t)row * Ndim + col] = acc[i][j][r] + bv;
                }
            }
        }
    } else {
        const int t = n0 >> 7, part = t % 3, h = t / 3;
        float bv[4];
#pragma unroll
        for (int j = 0; j < 4; j++)
            bv[j] = bias[n0 + wc*64 + j*16 + lrow];

#pragma unroll
        for (int i = 0; i < 4; i++) {
            const int rowb = m0 + wr*64 + i*16 + (lane >> 4)*4;
            const int b = rowb >> 11, sbase = rowb & 2047;
            if (part == 2) {
                size_t vb = ((size_t)(b*H_ + h)) * HD_ * S_;
#pragma unroll
                for (int j = 0; j < 4; j++) {
                    int d = wc*64 + j*16 + lrow;
                    ushort4 o;
                    o.x = f2bf(acc[i][j][0] + bv[j]);
                    o.y = f2bf(acc[i][j][1] + bv[j]);
                    o.z = f2bf(acc[i][j][2] + bv[j]);
                    o.w = f2bf(acc[i][j][3] + bv[j]);
                    *(ushort4*)&out2[vb + (size_t)d * S_ + sbase] = o;
                }
            } else {
                unsigned short* outp = (part == 0) ? (unsigned short*)out0 : out1;
                size_t qb = ((size_t)(b*H_ + h)) * S_ * HD_;
#pragma unroll
                for (int r = 0; r < 4; r++) {
                    int s = sbase + r;
                    float vals[4];
#pragma unroll
                    for (int j = 0; j < 4; j++)
                        vals[j] = acc[i][j][r] + bv[j];
                    if (wc == 0) {
                        float inv = exp2f(-(float)lrow * 0.8304817737218413f); // 10000^(-lrow/16)
                        float ang = (float)s * inv, sn, cs;
                        sincosf(ang, &sn, &cs);
                        float v0 = vals[0]*cs - vals[1]*sn;
                        float v1 = vals[1]*cs + vals[0]*sn;
                        vals[0] = v0; vals[1] = v1;
                    }
#pragma unroll
                    for (int j = 0; j < 4; j++)
                        outp[qb + (size_t)s * HD_ + wc*64 + j*16 + lrow] = f2bf(vals[j]);
                }
            }
        }
    }
}

// ---------------------------------------------------------------- flash attention v4
// v3 + XOR-swizzled sK/sVt (T2, both-sides: pre-swizzled GLDS source column +
// swizzled ds_read). Removes the 16-way bank conflict on every K/V MFMA
// operand read (was 4.6e7 conflict cycles/dispatch).
// Swizzle: 16B-chunk index ^= (row & 7); LDS stays linear (GLDS writes
// base+lane*16), the global source column carries the inverse permutation.
__global__ __launch_bounds__(256) void flash3_kernel(
    const unsigned short* __restrict__ Qg,
    const unsigned short* __restrict__ Kg,
    const unsigned short* __restrict__ Vt,
    unsigned short* __restrict__ ctx)
{
    __shared__ unsigned short sK[64 * 128];   // K tile [key][d] (also Q staging), swizzled
    __shared__ unsigned short sVt[128 * 64];  // V^T tile [d][key], swizzled
    __shared__ float          sS[64 * 65];    // fp32 scores [q][k], padded
    __shared__ unsigned short sP[64 * 72];    // bf16 probs [q][k], padded
    __shared__ float sM[64], sL[64], sAl[64]; // per-row online-softmax state

    const int tid = threadIdx.x, lane = tid & 63, wave = tid >> 6;
    const int bh = blockIdx.y, q0 = blockIdx.x * 64;
    const int b = bh / H_, h = bh % H_;
    const unsigned short* Qb = Qg + (size_t)bh * S_ * HD_;
    const unsigned short* Kb = Kg + (size_t)bh * S_ * HD_;
    const unsigned short* Vb = Vt + (size_t)bh * HD_ * S_;
    const int lrow = lane & 15, quad = lane >> 4, lk = quad * 8;
    const int sw = lrow & 7;                       // read-side swizzle key
    const int qkcol = ((tid & 15) ^ ((tid >> 4) & 7)) * 8;  // sK staging src col (shorts)
    const int vcol  = ((tid & 7)  ^ ((tid >> 3) & 7)) * 8;  // sVt staging src col (shorts)

    if (quad == 0) { sM[wave*16 + lrow] = -1e30f; sL[wave*16 + lrow] = 0.f; }

#pragma unroll
    for (int c = 0; c < 4; c++)
        GLDS(Qb + (size_t)(q0 + c*16 + tid/16) * HD_ + qkcol, sK + c*2048 + tid*8);
    __syncthreads();
    bf16x8 qf[4];
#pragma unroll
    for (int c = 0; c < 4; c++)
        qf[c] = *(const bf16x8*)&sK[(wave*16 + lrow)*128 + ((c*4 + quad) ^ sw)*8];
    __syncthreads();

    f32x4 O[8] = {};

    const int ktiles = blockIdx.x + 1;
    for (int kt = 0; kt < ktiles; kt++) {
        const int ks = kt * 64;
#pragma unroll
        for (int c = 0; c < 4; c++)
            GLDS(Kb + (size_t)(ks + c*16 + tid/16) * HD_ + qkcol, sK  + c*2048 + tid*8);
#pragma unroll
        for (int c = 0; c < 4; c++)
            GLDS(Vb + (size_t)(c*32 + tid/8) * S_ + ks + vcol,    sVt + c*2048 + tid*8);
        __syncthreads();   // sK/sVt ready (shared across waves)

        // S = Q K^T; write to wave-private sS rows in plain [q][k]
        f32x4 sc[4] = {};
#pragma unroll
        for (int j = 0; j < 4; j++)
#pragma unroll
            for (int c = 0; c < 4; c++) {
                bf16x8 kf = *(const bf16x8*)&sK[(j*16 + lrow)*128 + ((c*4 + quad) ^ sw)*8];
                sc[j] = __builtin_amdgcn_mfma_f32_16x16x32_bf16(qf[c], kf, sc[j], 0, 0, 0);
            }
#pragma unroll
        for (int j = 0; j < 4; j++) {
            const int kcol = j*16 + lrow;
#pragma unroll
            for (int r = 0; r < 4; r++) {
                const int qrow = wave*16 + quad*4 + r;
                float v = sc[j][r] * SCALE_;
                sS[qrow*65 + kcol] = (ks + kcol <= q0 + qrow) ? v : -1e30f;
            }
        }

        // parallel online softmax: lane (quad,lrow) -> row lrow, cols quad*16..+15
        {
            const int row = wave*16 + lrow;
            const float* Sr = &sS[row*65 + quad*16];
            float tm = -1e30f;
#pragma unroll
            for (int c = 0; c < 16; c++) tm = fmaxf(tm, Sr[c]);
            tm = fmaxf(tm, __shfl_xor(tm, 16, 64));
            tm = fmaxf(tm, __shfl_xor(tm, 32, 64));
            float mprev = sM[row];
            float mn = fmaxf(mprev, tm);
            float alpha = __expf(mprev - mn);
            float sum = 0.f;
            unsigned short* Pr = &sP[row*72 + quad*16];
#pragma unroll
            for (int c4 = 0; c4 < 4; c4++) {
                ushort4 o;
                float p0 = __expf(Sr[c4*4+0] - mn);
                float p1 = __expf(Sr[c4*4+1] - mn);
                float p2 = __expf(Sr[c4*4+2] - mn);
                float p3 = __expf(Sr[c4*4+3] - mn);
                sum += p0 + p1 + p2 + p3;
                o.x = f2bf(p0); o.y = f2bf(p1); o.z = f2bf(p2); o.w = f2bf(p3);
                *(ushort4*)&Pr[c4*4] = o;
            }
            sum += __shfl_xor(sum, 16, 64);
            sum += __shfl_xor(sum, 32, 64);
            if (quad == 0) {
                sM[row] = mn;
                sL[row] = sL[row]*alpha + sum;
                sAl[row] = alpha;
            }
        }

        // rescale O, then O += P V  (sP/sAl wave-private; wave-ordered LDS)
        float al[4];
#pragma unroll
        for (int r = 0; r < 4; r++) al[r] = sAl[wave*16 + quad*4 + r];
#pragma unroll
        for (int jo = 0; jo < 8; jo++)
#pragma unroll
            for (int r = 0; r < 4; r++) O[jo][r] *= al[r];
#pragma unroll
        for (int c = 0; c < 2; c++) {
            bf16x8 pf = *(const bf16x8*)&sP[(wave*16 + lrow)*72 + c*32 + lk];
#pragma unroll
            for (int jo = 0; jo < 8; jo++) {
                bf16x8 vf = *(const bf16x8*)&sVt[(jo*16 + lrow)*64 + ((c*4 + quad) ^ sw)*8];
                O[jo] = __builtin_amdgcn_mfma_f32_16x16x32_bf16(pf, vf, O[jo], 0, 0, 0);
            }
        }
        __syncthreads();   // all waves done with sK/sVt before next GLDS
    }

    float li[4];
#pragma unroll
    for (int r = 0; r < 4; r++) li[r] = sL[wave*16 + quad*4 + r];
#pragma unroll
    for (int jo = 0; jo < 8; jo++) {
        const int dcol = jo*16 + lrow;
#pragma unroll
        for (int r = 0; r < 4; r++) {
            const int srow = q0 + wave*16 + quad*4 + r;
            ctx[((size_t)b * S_ + srow) * D_ + h*HD_ + dcol] = f2bf(O[jo][r] / li[r]);
        }
    }
}

// ---------------------------------------------------------------- launch
extern "C" void kernel_launch(void* const* d_in, const int* in_sizes, int n_in,
                              void* d_out, int out_size, void* d_ws, size_t ws_size,
                              hipStream_t stream) {
    const float* hs   = (const float*)d_in[0];
    // d_in[1] attention_mask: all ones, unused by the reference math
    const float* Wqkv = (const float*)d_in[2];
    const float* bqkv = (const float*)d_in[3];
    const float* Wd   = (const float*)d_in[4];
    const float* bd   = (const float*)d_in[5];
    float* out = (float*)d_out;

    char* ws  = (char*)d_ws;
    char* dob = (char*)d_out;
    // Memory map (base footprint 32 MiB, verified r4-r6):
    //   ws[0,16MiB):   Vt [bh][d][s]; WdT at ws[0,8MiB) after flash.
    //   ws[16,24MiB):  TW (per-chunk W^T) during gemm1; ctx ws[16,32) after.
    //   ws[32,48MiB):  Xbf (optional, only if ws_size >= 48MiB).
    //   d_out[0,16):   Qg ; d_out[16,32): Kg (dead before gemm2 writes).
    unsigned short* Vt  = (unsigned short*)(ws);
    unsigned short* WdT = (unsigned short*)(ws);
    unsigned short* TW  = (unsigned short*)(ws + 16777216);
    unsigned short* ctx = (unsigned short*)(ws + 16777216);
    unsigned short* Qg  = (unsigned short*)(dob);
    unsigned short* Kg  = (unsigned short*)(dob + 16777216);

    const bool have_xbf = (ws_size >= (size_t)50331648);
    unsigned short* Xbf = (unsigned short*)(ws + 33554432);

    // 1. QKV projection in 3 column-chunks: transpose chunk -> GEMM (+RoPE/split)
    if (have_xbf) {
        int n4 = M_ * D_ / 4;
        cast_bf16_kernel<<<dim3((n4 + 255) / 256), dim3(256), 0, stream>>>(hs, Xbf, n4);
        for (int c = 0; c < 3; c++) {
            transpose_cast_kernel<<<dim3(64, 64), dim3(256), 0, stream>>>(
                Wqkv + c*2048, TW, D_, N3_);
            gemm_bt2_kernel<1, 1><<<dim3(16, 32), dim3(256), 0, stream>>>(
                Xbf, TW, bqkv, Qg, Kg, Vt, N3_, D_, c*2048);
        }
    } else {
        for (int c = 0; c < 3; c++) {
            transpose_cast_kernel<<<dim3(64, 64), dim3(256), 0, stream>>>(
                Wqkv + c*2048, TW, D_, N3_);
            gemm_bt2_kernel<0, 1><<<dim3(16, 32), dim3(256), 0, stream>>>(
                hs, TW, bqkv, Qg, Kg, Vt, N3_, D_, c*2048);
        }
    }
    // 2. causal flash attention (parallel wave-private softmax)
    flash3_kernel<<<dim3(S_/64, B_*H_), dim3(256), 0, stream>>>(Qg, Kg, Vt, ctx);
    // 3. W_dense^T (Vt dead), then dense projection, fp32 out
    transpose_cast_kernel<<<dim3(64, 64), dim3(256), 0, stream>>>(
        Wd, WdT, D_, D_);
    gemm_bt2_kernel<1, 0><<<dim3(16, 32), dim3(256), 0, stream>>>(
        ctx, WdT, bd, out, nullptr, nullptr, D_, D_, 0);
}

// Round 4
// 453.579 us; speedup vs baseline: 1.3606x; 1.1439x over previous
//
#include <hip/hip_runtime.h>
#include <hip/hip_bf16.h>
#include <math.h>

#define B_   2
#define S_   2048
#define D_   2048
#define H_   16
#define HD_  128
#define ROT_ 32
#define M_   (B_*S_)    // 4096 tokens
#define N3_  (3*D_)     // 6144

static constexpr float SCALE_ = 0.08838834764831845f;  // 1/sqrt(128)

typedef __attribute__((ext_vector_type(4))) float  f32x4;
typedef __attribute__((ext_vector_type(8))) __bf16 bf16x8;

__device__ inline unsigned short f2bf(float f) {
    unsigned int u = __builtin_bit_cast(unsigned int, f);
    unsigned int r = (u + 0x7fffu + ((u >> 16) & 1u)) >> 16;
    return (unsigned short)r;
}
__device__ inline float bf2f(unsigned short h) {
    unsigned int u = ((unsigned int)h) << 16;
    return __builtin_bit_cast(float, u);
}

#define GLDS(g, l) __builtin_amdgcn_global_load_lds(                          \
    (const __attribute__((address_space(1))) void*)(g),                       \
    (__attribute__((address_space(3))) void*)(l), 16, 0, 0)

// ---------------------------------------------------------------- cast fp32 -> bf16
__global__ void cast_bf16_kernel(const float* __restrict__ src,
                                 unsigned short* __restrict__ dst, int n4) {
    int i = blockIdx.x * blockDim.x + threadIdx.x;
    if (i < n4) {
        float4 v = ((const float4*)src)[i];
        ushort4 o;
        o.x = f2bf(v.x); o.y = f2bf(v.y); o.z = f2bf(v.z); o.w = f2bf(v.w);
        ((ushort4*)dst)[i] = o;
    }
}

// ------------------------------------------- transpose+cast (conflict-free)
__global__ __launch_bounds__(256) void transpose_cast_kernel(
    const float* __restrict__ src, unsigned short* __restrict__ dst,
    int R, int ldS)
{
    __shared__ float tile[32][33];
    int c0 = blockIdx.x * 32, r0 = blockIdx.y * 32;
    int tx = threadIdx.x & 31, ty = threadIdx.x >> 5;  // ty 0..7
#pragma unroll
    for (int i = 0; i < 4; i++)
        tile[ty + i*8][tx] = src[(size_t)(r0 + ty + i*8) * ldS + c0 + tx];
    __syncthreads();
#pragma unroll
    for (int i = 0; i < 4; i++)
        dst[(size_t)(c0 + ty + i*8) * R + r0 + tx] = f2bf(tile[tx][ty + i*8]);
}

// ---------------------------------------------------------------- GEMM (B^T, GLDS both sides)
// (verified r6) C = A @ B + bias. A: M x K row-major (fp32->register cast if
// ABF16==0; bf16 GLDS if 1). BT: bf16 [n_local][K]. n0 = n_base + bx*128.
// MODE 0: fp32 C (+bias). MODE 1: qkv epilogue (bias+RoPE+head-split scatter).
// r9: XCD-chunked block swizzle (grid is always (16,32)): XCD x owns 4
//     M-panels (2MB A resident in its L2) x all 16 N-tiles.
//     Q (part==0) pre-scaled by 1/sqrt(HD) (commutes with RoPE; exact).
template <int ABF16, int MODE>
__global__ __launch_bounds__(256) void gemm_bt2_kernel(
    const void* __restrict__ Aptr,
    const unsigned short* __restrict__ BT,
    const float* __restrict__ bias,
    void* __restrict__ out0,
    unsigned short* __restrict__ out1,
    unsigned short* __restrict__ out2,
    int Ndim, int K, int n_base)
{
    __shared__ unsigned short sA[128 * 32];
    __shared__ unsigned short sB[128 * 32];
    const int tid  = threadIdx.x;
    // XCD-chunked swizzle: dispatch id d -> XCD d&7 (round-robin heuristic).
    // XCD x gets i = d>>3 in [0,64): by' = x*4 + (i>>4), bx' = i&15. Bijective.
    const int d    = (int)blockIdx.x + (int)blockIdx.y * (int)gridDim.x;
    const int xcd  = d & 7, ii = d >> 3;
    const int m0   = (xcd * 4 + (ii >> 4)) * 128;
    const int nloc = (ii & 15) * 128;
    const int n0   = n_base + nloc;
    const int lane = tid & 63, wave = tid >> 6;
    const int wr = wave >> 1, wc = wave & 1;
    const int lrow = lane & 15, lk = (lane >> 4) * 8;

    f32x4 acc[4][4] = {};

    const unsigned short* Bg = BT + (size_t)(nloc + tid/4) * K + (tid & 3) * 8;

    for (int k0 = 0; k0 < K; k0 += 32) {
        if (ABF16) {
            const unsigned short* Ab = (const unsigned short*)Aptr;
#pragma unroll
            for (int c = 0; c < 2; c++)
                GLDS(Ab + (size_t)(m0 + c*64 + tid/4) * K + k0 + (tid & 3) * 8,
                     sA + c*2048 + tid*8);
        } else {
            const float* Af = (const float*)Aptr;
#pragma unroll
            for (int p = 0; p < 4; p++) {
                int row = p*32 + tid/8, col = (tid & 7) * 4;
                float4 v = *(const float4*)&Af[(size_t)(m0 + row) * K + k0 + col];
                ushort4 o;
                o.x = f2bf(v.x); o.y = f2bf(v.y); o.z = f2bf(v.z); o.w = f2bf(v.w);
                *(ushort4*)&sA[row*32 + col] = o;
            }
        }
#pragma unroll
        for (int c = 0; c < 2; c++)
            GLDS(Bg + (size_t)c*64*K + k0, sB + c*2048 + tid*8);
        __syncthreads();
        bf16x8 af[4], bfj[4];
#pragma unroll
        for (int i = 0; i < 4; i++)
            af[i]  = *(const bf16x8*)&sA[(wr*64 + i*16 + lrow)*32 + lk];
#pragma unroll
        for (int j = 0; j < 4; j++)
            bfj[j] = *(const bf16x8*)&sB[(wc*64 + j*16 + lrow)*32 + lk];
#pragma unroll
        for (int i = 0; i < 4; i++)
#pragma unroll
            for (int j = 0; j < 4; j++)
                acc[i][j] = __builtin_amdgcn_mfma_f32_16x16x32_bf16(af[i], bfj[j], acc[i][j], 0, 0, 0);
        __syncthreads();
    }

    if (MODE == 0) {
#pragma unroll
        for (int i = 0; i < 4; i++) {
#pragma unroll
            for (int j = 0; j < 4; j++) {
                int col = n0 + wc*64 + j*16 + lrow;
                float bv = bias[col];
#pragma unroll
                for (int r = 0; r < 4; r++) {
                    int row = m0 + wr*64 + i*16 + (lane >> 4)*4 + r;
                    ((float*)out0)[(size_t)row * Ndim + col] = acc[i][j][r] + bv;
                }
            }
        }
    } else {
        const int t = n0 >> 7, part = t % 3, h = t / 3;
        float bv[4];
#pragma unroll
        for (int j = 0; j < 4; j++)
            bv[j] = bias[n0 + wc*64 + j*16 + lrow];

#pragma unroll
        for (int i = 0; i < 4; i++) {
            const int rowb = m0 + wr*64 + i*16 + (lane >> 4)*4;
            const int b = rowb >> 11, sbase = rowb & 2047;
            if (part == 2) {
                size_t vb = ((size_t)(b*H_ + h)) * HD_ * S_;
#pragma unroll
                for (int j = 0; j < 4; j++) {
                    int dd = wc*64 + j*16 + lrow;
                    ushort4 o;
                    o.x = f2bf(acc[i][j][0] + bv[j]);
                    o.y = f2bf(acc[i][j][1] + bv[j]);
                    o.z = f2bf(acc[i][j][2] + bv[j]);
                    o.w = f2bf(acc[i][j][3] + bv[j]);
                    *(ushort4*)&out2[vb + (size_t)dd * S_ + sbase] = o;
                }
            } else {
                unsigned short* outp = (part == 0) ? (unsigned short*)out0 : out1;
                size_t qb = ((size_t)(b*H_ + h)) * S_ * HD_;
#pragma unroll
                for (int r = 0; r < 4; r++) {
                    int s = sbase + r;
                    float vals[4];
#pragma unroll
                    for (int j = 0; j < 4; j++)
                        vals[j] = acc[i][j][r] + bv[j];
                    if (part == 0) {
#pragma unroll
                        for (int j = 0; j < 4; j++)
                            vals[j] *= SCALE_;   // fold 1/sqrt(HD) into Q (exact)
                    }
                    if (wc == 0) {
                        float inv = exp2f(-(float)lrow * 0.8304817737218413f); // 10000^(-lrow/16)
                        float ang = (float)s * inv, sn, cs;
                        sincosf(ang, &sn, &cs);
                        float v0 = vals[0]*cs - vals[1]*sn;
                        float v1 = vals[1]*cs + vals[0]*sn;
                        vals[0] = v0; vals[1] = v1;
                    }
#pragma unroll
                    for (int j = 0; j < 4; j++)
                        outp[qb + (size_t)s * HD_ + wc*64 + j*16 + lrow] = f2bf(vals[j]);
                }
            }
        }
    }
}

// ---------------------------------------------------------------- flash attention v4c
// = the VERIFIED v4 body (R1, 168us) with only exact transforms:
//   - XCD-chunked grid swizzle (bijective), heavy q-tiles first.
//   - causal mask applied only on the diagonal k-tile; condition kcol <= qrow
//     with qrow = wave*16 + quad*4 + r (R3 had a cancelling-terms typo here
//     that over-masked waves 1-3; fixed).
//   - SCALE_ pre-folded into Q by the QKV epilogue.
//   - compiler memory fence between softmax LDS writes and PV LDS reads.
__global__ __launch_bounds__(256) void flash3_kernel(
    const unsigned short* __restrict__ Qg,
    const unsigned short* __restrict__ Kg,
    const unsigned short* __restrict__ Vt,
    unsigned short* __restrict__ ctx)
{
    __shared__ unsigned short sK[64 * 128];   // K tile [key][d] (also Q staging), swizzled
    __shared__ unsigned short sVt[128 * 64];  // V^T tile [d][key], swizzled
    __shared__ float          sS[64 * 65];    // fp32 scores [q][k], padded
    __shared__ unsigned short sP[64 * 72];    // bf16 probs [q][k], padded
    __shared__ float sM[64], sL[64], sAl[64]; // per-row online-softmax state

    const int tid = threadIdx.x, lane = tid & 63, wave = tid >> 6;
    // XCD-chunked bijection: dispatch d -> xcd = d&7, i = d>>3 in [0,128):
    //   bh = xcd*4 + (i&3), q-tile index descends (heavy first).
    const int d   = (int)blockIdx.x + (int)blockIdx.y * (int)gridDim.x;
    const int xcd = d & 7, ii = d >> 3;
    const int bh  = xcd * 4 + (ii & 3);
    const int q0  = (31 - (ii >> 2)) * 64;
    const int b = bh / H_, h = bh % H_;
    const unsigned short* Qb = Qg + (size_t)bh * S_ * HD_;
    const unsigned short* Kb = Kg + (size_t)bh * S_ * HD_;
    const unsigned short* Vb = Vt + (size_t)bh * HD_ * S_;
    const int lrow = lane & 15, quad = lane >> 4, lk = quad * 8;
    const int sw = lrow & 7;                       // read-side swizzle key
    const int qkcol = ((tid & 15) ^ ((tid >> 4) & 7)) * 8;  // sK staging src col (shorts)
    const int vcol  = ((tid & 7)  ^ ((tid >> 3) & 7)) * 8;  // sVt staging src col (shorts)

    if (quad == 0) { sM[wave*16 + lrow] = -1e30f; sL[wave*16 + lrow] = 0.f; }

#pragma unroll
    for (int c = 0; c < 4; c++)
        GLDS(Qb + (size_t)(q0 + c*16 + tid/16) * HD_ + qkcol, sK + c*2048 + tid*8);
    __syncthreads();
    bf16x8 qf[4];
#pragma unroll
    for (int c = 0; c < 4; c++)
        qf[c] = *(const bf16x8*)&sK[(wave*16 + lrow)*128 + ((c*4 + quad) ^ sw)*8];
    __syncthreads();

    f32x4 O[8] = {};

    const int ktiles = (q0 >> 6) + 1;
    for (int kt = 0; kt < ktiles; kt++) {
        const int ks = kt * 64;
#pragma unroll
        for (int c = 0; c < 4; c++)
            GLDS(Kb + (size_t)(ks + c*16 + tid/16) * HD_ + qkcol, sK  + c*2048 + tid*8);
#pragma unroll
        for (int c = 0; c < 4; c++)
            GLDS(Vb + (size_t)(c*32 + tid/8) * S_ + ks + vcol,    sVt + c*2048 + tid*8);
        __syncthreads();   // sK/sVt ready (shared across waves)

        // S = Q K^T (Q pre-scaled); write to wave-private sS rows in plain [q][k]
        f32x4 sc[4] = {};
#pragma unroll
        for (int j = 0; j < 4; j++)
#pragma unroll
            for (int c = 0; c < 4; c++) {
                bf16x8 kf = *(const bf16x8*)&sK[(j*16 + lrow)*128 + ((c*4 + quad) ^ sw)*8];
                sc[j] = __builtin_amdgcn_mfma_f32_16x16x32_bf16(qf[c], kf, sc[j], 0, 0, 0);
            }
        if (kt == ktiles - 1) {
            // diagonal tile (ks == q0): mask kcol > qrow, block-local indices
#pragma unroll
            for (int j = 0; j < 4; j++) {
                const int kcol = j*16 + lrow;
#pragma unroll
                for (int r = 0; r < 4; r++) {
                    const int qrow = wave*16 + quad*4 + r;
                    sS[qrow*65 + kcol] = (kcol <= qrow) ? sc[j][r] : -1e30f;
                }
            }
        } else {
#pragma unroll
            for (int j = 0; j < 4; j++) {
                const int kcol = j*16 + lrow;
#pragma unroll
                for (int r = 0; r < 4; r++) {
                    const int qrow = wave*16 + quad*4 + r;
                    sS[qrow*65 + kcol] = sc[j][r];
                }
            }
        }

        // parallel online softmax: lane (quad,lrow) -> row lrow, cols quad*16..+15
        {
            const int row = wave*16 + lrow;
            const float* Sr = &sS[row*65 + quad*16];
            float tm = -1e30f;
#pragma unroll
            for (int c = 0; c < 16; c++) tm = fmaxf(tm, Sr[c]);
            tm = fmaxf(tm, __shfl_xor(tm, 16, 64));
            tm = fmaxf(tm, __shfl_xor(tm, 32, 64));
            float mprev = sM[row];
            float mn = fmaxf(mprev, tm);
            float alpha = __expf(mprev - mn);
            float sum = 0.f;
            unsigned short* Pr = &sP[row*72 + quad*16];
#pragma unroll
            for (int c4 = 0; c4 < 4; c4++) {
                ushort4 o;
                float p0 = __expf(Sr[c4*4+0] - mn);
                float p1 = __expf(Sr[c4*4+1] - mn);
                float p2 = __expf(Sr[c4*4+2] - mn);
                float p3 = __expf(Sr[c4*4+3] - mn);
                sum += p0 + p1 + p2 + p3;
                o.x = f2bf(p0); o.y = f2bf(p1); o.z = f2bf(p2); o.w = f2bf(p3);
                *(ushort4*)&Pr[c4*4] = o;
            }
            sum += __shfl_xor(sum, 16, 64);
            sum += __shfl_xor(sum, 32, 64);
            if (quad == 0) {
                sM[row] = mn;
                sL[row] = sL[row]*alpha + sum;
                sAl[row] = alpha;
            }
        }
        asm volatile("" ::: "memory");   // order softmax LDS writes before PV LDS reads

        // rescale O, then O += P V  (sP/sAl wave-private; wave-ordered LDS)
        float al[4];
#pragma unroll
        for (int r = 0; r < 4; r++) al[r] = sAl[wave*16 + quad*4 + r];
#pragma unroll
        for (int jo = 0; jo < 8; jo++)
#pragma unroll
            for (int r = 0; r < 4; r++) O[jo][r] *= al[r];
#pragma unroll
        for (int c = 0; c < 2; c++) {
            bf16x8 pf = *(const bf16x8*)&sP[(wave*16 + lrow)*72 + c*32 + lk];
#pragma unroll
            for (int jo = 0; jo < 8; jo++) {
                bf16x8 vf = *(const bf16x8*)&sVt[(jo*16 + lrow)*64 + ((c*4 + quad) ^ sw)*8];
                O[jo] = __builtin_amdgcn_mfma_f32_16x16x32_bf16(pf, vf, O[jo], 0, 0, 0);
            }
        }
        __syncthreads();   // all waves done with sK/sVt before next GLDS
    }

    float li[4];
#pragma unroll
    for (int r = 0; r < 4; r++) li[r] = sL[wave*16 + quad*4 + r];
#pragma unroll
    for (int jo = 0; jo < 8; jo++) {
        const int dcol = jo*16 + lrow;
#pragma unroll
        for (int r = 0; r < 4; r++) {
            const int srow = q0 + wave*16 + quad*4 + r;
            ctx[((size_t)b * S_ + srow) * D_ + h*HD_ + dcol] = f2bf(O[jo][r] / li[r]);
        }
    }
}

// ---------------------------------------------------------------- launch
extern "C" void kernel_launch(void* const* d_in, const int* in_sizes, int n_in,
                              void* d_out, int out_size, void* d_ws, size_t ws_size,
                              hipStream_t stream) {
    const float* hs   = (const float*)d_in[0];
    // d_in[1] attention_mask: all ones, unused by the reference math
    const float* Wqkv = (const float*)d_in[2];
    const float* bqkv = (const float*)d_in[3];
    const float* Wd   = (const float*)d_in[4];
    const float* bd   = (const float*)d_in[5];
    float* out = (float*)d_out;

    char* ws  = (char*)d_ws;
    char* dob = (char*)d_out;
    // Memory map (base footprint 32 MiB, verified r4-r6):
    //   ws[0,16MiB):   Vt [bh][d][s]; WdT at ws[0,8MiB) after flash.
    //   ws[16,24MiB):  TW (per-chunk W^T) during gemm1; ctx ws[16,32) after.
    //   ws[32,48MiB):  Xbf (optional, only if ws_size >= 48MiB).
    //   d_out[0,16):   Qg ; d_out[16,32): Kg (dead before gemm2 writes).
    unsigned short* Vt  = (unsigned short*)(ws);
    unsigned short* WdT = (unsigned short*)(ws);
    unsigned short* TW  = (unsigned short*)(ws + 16777216);
    unsigned short* ctx = (unsigned short*)(ws + 16777216);
    unsigned short* Qg  = (unsigned short*)(dob);
    unsigned short* Kg  = (unsigned short*)(dob + 16777216);

    const bool have_xbf = (ws_size >= (size_t)50331648);
    unsigned short* Xbf = (unsigned short*)(ws + 33554432);

    // 1. QKV projection in 3 column-chunks: transpose chunk -> GEMM (+RoPE/split)
    if (have_xbf) {
        int n4 = M_ * D_ / 4;
        cast_bf16_kernel<<<dim3((n4 + 255) / 256), dim3(256), 0, stream>>>(hs, Xbf, n4);
        for (int c = 0; c < 3; c++) {
            transpose_cast_kernel<<<dim3(64, 64), dim3(256), 0, stream>>>(
                Wqkv + c*2048, TW, D_, N3_);
            gemm_bt2_kernel<1, 1><<<dim3(16, 32), dim3(256), 0, stream>>>(
                Xbf, TW, bqkv, Qg, Kg, Vt, N3_, D_, c*2048);
        }
    } else {
        for (int c = 0; c < 3; c++) {
            transpose_cast_kernel<<<dim3(64, 64), dim3(256), 0, stream>>>(
                Wqkv + c*2048, TW, D_, N3_);
            gemm_bt2_kernel<0, 1><<<dim3(16, 32), dim3(256), 0, stream>>>(
                hs, TW, bqkv, Qg, Kg, Vt, N3_, D_, c*2048);
        }
    }
    // 2. causal flash attention (verified softmax structure, swizzled grid)
    flash3_kernel<<<dim3(S_/64, B_*H_), dim3(256), 0, stream>>>(Qg, Kg, Vt, ctx);
    // 3. W_dense^T (Vt dead), then dense projection, fp32 out
    transpose_cast_kernel<<<dim3(64, 64), dim3(256), 0, stream>>>(
        Wd, WdT, D_, D_);
    gemm_bt2_kernel<1, 0><<<dim3(16, 32), dim3(256), 0, stream>>>(
        ctx, WdT, bd, out, nullptr, nullptr, D_, D_, 0);
}

// Round 5
// 424.470 us; speedup vs baseline: 1.4539x; 1.0686x over previous
//
#include <hip/hip_runtime.h>
#include <hip/hip_bf16.h>
#include <math.h>

#define B_   2
#define S_   2048
#define D_   2048
#define H_   16
#define HD_  128
#define ROT_ 32
#define M_   (B_*S_)    // 4096 tokens
#define N3_  (3*D_)     // 6144

static constexpr float SCALE_ = 0.08838834764831845f;  // 1/sqrt(128)

typedef __attribute__((ext_vector_type(4))) float  f32x4;
typedef __attribute__((ext_vector_type(8))) __bf16 bf16x8;

__device__ inline unsigned short f2bf(float f) {
    unsigned int u = __builtin_bit_cast(unsigned int, f);
    unsigned int r = (u + 0x7fffu + ((u >> 16) & 1u)) >> 16;
    return (unsigned short)r;
}
__device__ inline float bf2f(unsigned short h) {
    unsigned int u = ((unsigned int)h) << 16;
    return __builtin_bit_cast(float, u);
}

#define GLDS(g, l) __builtin_amdgcn_global_load_lds(                          \
    (const __attribute__((address_space(1))) void*)(g),                       \
    (__attribute__((address_space(3))) void*)(l), 16, 0, 0)

// ---------------------------------------------------------------- cast fp32 -> bf16
__global__ void cast_bf16_kernel(const float* __restrict__ src,
                                 unsigned short* __restrict__ dst, int n4) {
    int i = blockIdx.x * blockDim.x + threadIdx.x;
    if (i < n4) {
        float4 v = ((const float4*)src)[i];
        ushort4 o;
        o.x = f2bf(v.x); o.y = f2bf(v.y); o.z = f2bf(v.z); o.w = f2bf(v.w);
        ((ushort4*)dst)[i] = o;
    }
}

// ------------------------------------------- transpose+cast (conflict-free)
__global__ __launch_bounds__(256) void transpose_cast_kernel(
    const float* __restrict__ src, unsigned short* __restrict__ dst,
    int R, int ldS)
{
    __shared__ float tile[32][33];
    int c0 = blockIdx.x * 32, r0 = blockIdx.y * 32;
    int tx = threadIdx.x & 31, ty = threadIdx.x >> 5;  // ty 0..7
#pragma unroll
    for (int i = 0; i < 4; i++)
        tile[ty + i*8][tx] = src[(size_t)(r0 + ty + i*8) * ldS + c0 + tx];
    __syncthreads();
#pragma unroll
    for (int i = 0; i < 4; i++)
        dst[(size_t)(c0 + ty + i*8) * R + r0 + tx] = f2bf(tile[tx][ty + i*8]);
}

// ---------------------------------------------------------------- GEMM (B^T, GLDS both sides)
// r10: 8-wave version (512 threads). Same 128x128 tile, same 2-barrier
// K-loop, same LDS layout as the verified r6 structure — only the wave->
// sub-tile decomposition changes: 8 waves of 32x64 (acc[2][4]) instead of
// 4 waves of 64x64. Rationale: grid is 512 blocks = 2 blocks/CU (grid-
// limited), so 4-wave blocks ran at 2 waves/SIMD — too few to cover the
// vmcnt(0)+barrier drain (m114 overlap needs ~3+). 8-wave blocks give
// 4 waves/SIMD at the same grid. Staging: one GLDS round per buffer
// (512 lanes x 16B = 8KB = full tile).
// MODE 0: fp32 C (+bias). MODE 1: qkv epilogue (bias+RoPE+head-split scatter).
// Q (part==0) pre-scaled by 1/sqrt(HD) (commutes with RoPE; exact).
template <int ABF16, int MODE>
__global__ __launch_bounds__(512) void gemm_bt2_kernel(
    const void* __restrict__ Aptr,
    const unsigned short* __restrict__ BT,
    const float* __restrict__ bias,
    void* __restrict__ out0,
    unsigned short* __restrict__ out1,
    unsigned short* __restrict__ out2,
    int Ndim, int K, int n_base)
{
    __shared__ unsigned short sA[128 * 32];
    __shared__ unsigned short sB[128 * 32];
    const int tid  = threadIdx.x;
    // XCD-chunked swizzle: dispatch id d -> XCD d&7 (round-robin heuristic).
    // XCD x gets i = d>>3 in [0,64): by' = x*4 + (i>>4), bx' = i&15. Bijective.
    const int d    = (int)blockIdx.x + (int)blockIdx.y * (int)gridDim.x;
    const int xcd  = d & 7, ii = d >> 3;
    const int m0   = (xcd * 4 + (ii >> 4)) * 128;
    const int nloc = (ii & 15) * 128;
    const int n0   = n_base + nloc;
    const int lane = tid & 63, wave = tid >> 6;          // 8 waves
    const int wr = wave >> 1, wc = wave & 1;             // wr 0..3, wc 0..1
    const int lrow = lane & 15, quad = lane >> 4, lk = quad * 8;

    f32x4 acc[2][4] = {};

    const unsigned short* Bg = BT + (size_t)(nloc + tid/4) * K + (tid & 3) * 8;

    for (int k0 = 0; k0 < K; k0 += 32) {
        if (ABF16) {
            const unsigned short* Ab = (const unsigned short*)Aptr;
            GLDS(Ab + (size_t)(m0 + tid/4) * K + k0 + (tid & 3) * 8, sA + tid*8);
        } else {
            const float* Af = (const float*)Aptr;
#pragma unroll
            for (int p = 0; p < 2; p++) {
                int row = p*64 + tid/8, col = (tid & 7) * 4;
                float4 v = *(const float4*)&Af[(size_t)(m0 + row) * K + k0 + col];
                ushort4 o;
                o.x = f2bf(v.x); o.y = f2bf(v.y); o.z = f2bf(v.z); o.w = f2bf(v.w);
                *(ushort4*)&sA[row*32 + col] = o;
            }
        }
        GLDS(Bg + k0, sB + tid*8);
        __syncthreads();
        bf16x8 af[2], bfj[4];
#pragma unroll
        for (int i = 0; i < 2; i++)
            af[i]  = *(const bf16x8*)&sA[(wr*32 + i*16 + lrow)*32 + lk];
#pragma unroll
        for (int j = 0; j < 4; j++)
            bfj[j] = *(const bf16x8*)&sB[(wc*64 + j*16 + lrow)*32 + lk];
#pragma unroll
        for (int i = 0; i < 2; i++)
#pragma unroll
            for (int j = 0; j < 4; j++)
                acc[i][j] = __builtin_amdgcn_mfma_f32_16x16x32_bf16(af[i], bfj[j], acc[i][j], 0, 0, 0);
        __syncthreads();
    }

    if (MODE == 0) {
#pragma unroll
        for (int i = 0; i < 2; i++) {
#pragma unroll
            for (int j = 0; j < 4; j++) {
                int col = n0 + wc*64 + j*16 + lrow;
                float bv = bias[col];
#pragma unroll
                for (int r = 0; r < 4; r++) {
                    int row = m0 + wr*32 + i*16 + quad*4 + r;
                    ((float*)out0)[(size_t)row * Ndim + col] = acc[i][j][r] + bv;
                }
            }
        }
    } else {
        const int t = n0 >> 7, part = t % 3, h = t / 3;
        float bv[4];
#pragma unroll
        for (int j = 0; j < 4; j++)
            bv[j] = bias[n0 + wc*64 + j*16 + lrow];

#pragma unroll
        for (int i = 0; i < 2; i++) {
            const int rowb = m0 + wr*32 + i*16 + quad*4;
            const int b = rowb >> 11, sbase = rowb & 2047;
            if (part == 2) {
                size_t vb = ((size_t)(b*H_ + h)) * HD_ * S_;
#pragma unroll
                for (int j = 0; j < 4; j++) {
                    int dd = wc*64 + j*16 + lrow;
                    ushort4 o;
                    o.x = f2bf(acc[i][j][0] + bv[j]);
                    o.y = f2bf(acc[i][j][1] + bv[j]);
                    o.z = f2bf(acc[i][j][2] + bv[j]);
                    o.w = f2bf(acc[i][j][3] + bv[j]);
                    *(ushort4*)&out2[vb + (size_t)dd * S_ + sbase] = o;
                }
            } else {
                unsigned short* outp = (part == 0) ? (unsigned short*)out0 : out1;
                size_t qb = ((size_t)(b*H_ + h)) * S_ * HD_;
#pragma unroll
                for (int r = 0; r < 4; r++) {
                    int s = sbase + r;
                    float vals[4];
#pragma unroll
                    for (int j = 0; j < 4; j++)
                        vals[j] = acc[i][j][r] + bv[j];
                    if (part == 0) {
#pragma unroll
                        for (int j = 0; j < 4; j++)
                            vals[j] *= SCALE_;   // fold 1/sqrt(HD) into Q (exact)
                    }
                    if (wc == 0) {
                        float inv = exp2f(-(float)lrow * 0.8304817737218413f); // 10000^(-lrow/16)
                        float ang = (float)s * inv, sn, cs;
                        sincosf(ang, &sn, &cs);
                        float v0 = vals[0]*cs - vals[1]*sn;
                        float v1 = vals[1]*cs + vals[0]*sn;
                        vals[0] = v0; vals[1] = v1;
                    }
#pragma unroll
                    for (int j = 0; j < 4; j++)
                        outp[qb + (size_t)s * HD_ + wc*64 + j*16 + lrow] = f2bf(vals[j]);
                }
            }
        }
    }
}

// ---------------------------------------------------------------- flash attention v4c
// (verified R4, 90us) XCD-chunked grid, diagonal-only mask, pre-scaled Q,
// fence between softmax LDS writes and PV LDS reads. UNCHANGED this round.
__global__ __launch_bounds__(256) void flash3_kernel(
    const unsigned short* __restrict__ Qg,
    const unsigned short* __restrict__ Kg,
    const unsigned short* __restrict__ Vt,
    unsigned short* __restrict__ ctx)
{
    __shared__ unsigned short sK[64 * 128];   // K tile [key][d] (also Q staging), swizzled
    __shared__ unsigned short sVt[128 * 64];  // V^T tile [d][key], swizzled
    __shared__ float          sS[64 * 65];    // fp32 scores [q][k], padded
    __shared__ unsigned short sP[64 * 72];    // bf16 probs [q][k], padded
    __shared__ float sM[64], sL[64], sAl[64]; // per-row online-softmax state

    const int tid = threadIdx.x, lane = tid & 63, wave = tid >> 6;
    // XCD-chunked bijection: dispatch d -> xcd = d&7, i = d>>3 in [0,128):
    //   bh = xcd*4 + (i&3), q-tile index descends (heavy first).
    const int d   = (int)blockIdx.x + (int)blockIdx.y * (int)gridDim.x;
    const int xcd = d & 7, ii = d >> 3;
    const int bh  = xcd * 4 + (ii & 3);
    const int q0  = (31 - (ii >> 2)) * 64;
    const int b = bh / H_, h = bh % H_;
    const unsigned short* Qb = Qg + (size_t)bh * S_ * HD_;
    const unsigned short* Kb = Kg + (size_t)bh * S_ * HD_;
    const unsigned short* Vb = Vt + (size_t)bh * HD_ * S_;
    const int lrow = lane & 15, quad = lane >> 4, lk = quad * 8;
    const int sw = lrow & 7;                       // read-side swizzle key
    const int qkcol = ((tid & 15) ^ ((tid >> 4) & 7)) * 8;  // sK staging src col (shorts)
    const int vcol  = ((tid & 7)  ^ ((tid >> 3) & 7)) * 8;  // sVt staging src col (shorts)

    if (quad == 0) { sM[wave*16 + lrow] = -1e30f; sL[wave*16 + lrow] = 0.f; }

#pragma unroll
    for (int c = 0; c < 4; c++)
        GLDS(Qb + (size_t)(q0 + c*16 + tid/16) * HD_ + qkcol, sK + c*2048 + tid*8);
    __syncthreads();
    bf16x8 qf[4];
#pragma unroll
    for (int c = 0; c < 4; c++)
        qf[c] = *(const bf16x8*)&sK[(wave*16 + lrow)*128 + ((c*4 + quad) ^ sw)*8];
    __syncthreads();

    f32x4 O[8] = {};

    const int ktiles = (q0 >> 6) + 1;
    for (int kt = 0; kt < ktiles; kt++) {
        const int ks = kt * 64;
#pragma unroll
        for (int c = 0; c < 4; c++)
            GLDS(Kb + (size_t)(ks + c*16 + tid/16) * HD_ + qkcol, sK  + c*2048 + tid*8);
#pragma unroll
        for (int c = 0; c < 4; c++)
            GLDS(Vb + (size_t)(c*32 + tid/8) * S_ + ks + vcol,    sVt + c*2048 + tid*8);
        __syncthreads();   // sK/sVt ready (shared across waves)

        // S = Q K^T (Q pre-scaled); write to wave-private sS rows in plain [q][k]
        f32x4 sc[4] = {};
#pragma unroll
        for (int j = 0; j < 4; j++)
#pragma unroll
            for (int c = 0; c < 4; c++) {
                bf16x8 kf = *(const bf16x8*)&sK[(j*16 + lrow)*128 + ((c*4 + quad) ^ sw)*8];
                sc[j] = __builtin_amdgcn_mfma_f32_16x16x32_bf16(qf[c], kf, sc[j], 0, 0, 0);
            }
        if (kt == ktiles - 1) {
            // diagonal tile (ks == q0): mask kcol > qrow, block-local indices
#pragma unroll
            for (int j = 0; j < 4; j++) {
                const int kcol = j*16 + lrow;
#pragma unroll
                for (int r = 0; r < 4; r++) {
                    const int qrow = wave*16 + quad*4 + r;
                    sS[qrow*65 + kcol] = (kcol <= qrow) ? sc[j][r] : -1e30f;
                }
            }
        } else {
#pragma unroll
            for (int j = 0; j < 4; j++) {
                const int kcol = j*16 + lrow;
#pragma unroll
                for (int r = 0; r < 4; r++) {
                    const int qrow = wave*16 + quad*4 + r;
                    sS[qrow*65 + kcol] = sc[j][r];
                }
            }
        }

        // parallel online softmax: lane (quad,lrow) -> row lrow, cols quad*16..+15
        {
            const int row = wave*16 + lrow;
            const float* Sr = &sS[row*65 + quad*16];
            float tm = -1e30f;
#pragma unroll
            for (int c = 0; c < 16; c++) tm = fmaxf(tm, Sr[c]);
            tm = fmaxf(tm, __shfl_xor(tm, 16, 64));
            tm = fmaxf(tm, __shfl_xor(tm, 32, 64));
            float mprev = sM[row];
            float mn = fmaxf(mprev, tm);
            float alpha = __expf(mprev - mn);
            float sum = 0.f;
            unsigned short* Pr = &sP[row*72 + quad*16];
#pragma unroll
            for (int c4 = 0; c4 < 4; c4++) {
                ushort4 o;
                float p0 = __expf(Sr[c4*4+0] - mn);
                float p1 = __expf(Sr[c4*4+1] - mn);
                float p2 = __expf(Sr[c4*4+2] - mn);
                float p3 = __expf(Sr[c4*4+3] - mn);
                sum += p0 + p1 + p2 + p3;
                o.x = f2bf(p0); o.y = f2bf(p1); o.z = f2bf(p2); o.w = f2bf(p3);
                *(ushort4*)&Pr[c4*4] = o;
            }
            sum += __shfl_xor(sum, 16, 64);
            sum += __shfl_xor(sum, 32, 64);
            if (quad == 0) {
                sM[row] = mn;
                sL[row] = sL[row]*alpha + sum;
                sAl[row] = alpha;
            }
        }
        asm volatile("" ::: "memory");   // order softmax LDS writes before PV LDS reads

        // rescale O, then O += P V  (sP/sAl wave-private; wave-ordered LDS)
        float al[4];
#pragma unroll
        for (int r = 0; r < 4; r++) al[r] = sAl[wave*16 + quad*4 + r];
#pragma unroll
        for (int jo = 0; jo < 8; jo++)
#pragma unroll
            for (int r = 0; r < 4; r++) O[jo][r] *= al[r];
#pragma unroll
        for (int c = 0; c < 2; c++) {
            bf16x8 pf = *(const bf16x8*)&sP[(wave*16 + lrow)*72 + c*32 + lk];
#pragma unroll
            for (int jo = 0; jo < 8; jo++) {
                bf16x8 vf = *(const bf16x8*)&sVt[(jo*16 + lrow)*64 + ((c*4 + quad) ^ sw)*8];
                O[jo] = __builtin_amdgcn_mfma_f32_16x16x32_bf16(pf, vf, O[jo], 0, 0, 0);
            }
        }
        __syncthreads();   // all waves done with sK/sVt before next GLDS
    }

    float li[4];
#pragma unroll
    for (int r = 0; r < 4; r++) li[r] = sL[wave*16 + quad*4 + r];
#pragma unroll
    for (int jo = 0; jo < 8; jo++) {
        const int dcol = jo*16 + lrow;
#pragma unroll
        for (int r = 0; r < 4; r++) {
            const int srow = q0 + wave*16 + quad*4 + r;
            ctx[((size_t)b * S_ + srow) * D_ + h*HD_ + dcol] = f2bf(O[jo][r] / li[r]);
        }
    }
}

// ---------------------------------------------------------------- launch
extern "C" void kernel_launch(void* const* d_in, const int* in_sizes, int n_in,
                              void* d_out, int out_size, void* d_ws, size_t ws_size,
                              hipStream_t stream) {
    const float* hs   = (const float*)d_in[0];
    // d_in[1] attention_mask: all ones, unused by the reference math
    const float* Wqkv = (const float*)d_in[2];
    const float* bqkv = (const float*)d_in[3];
    const float* Wd   = (const float*)d_in[4];
    const float* bd   = (const float*)d_in[5];
    float* out = (float*)d_out;

    char* ws  = (char*)d_ws;
    char* dob = (char*)d_out;
    // Memory map (base footprint 32 MiB, verified r4-r6):
    //   ws[0,16MiB):   Vt [bh][d][s]; WdT at ws[0,8MiB) after flash.
    //   ws[16,24MiB):  TW (per-chunk W^T) during gemm1; ctx ws[16,32) after.
    //   ws[32,48MiB):  Xbf (optional, only if ws_size >= 48MiB).
    //   d_out[0,16):   Qg ; d_out[16,32): Kg (dead before gemm2 writes).
    unsigned short* Vt  = (unsigned short*)(ws);
    unsigned short* WdT = (unsigned short*)(ws);
    unsigned short* TW  = (unsigned short*)(ws + 16777216);
    unsigned short* ctx = (unsigned short*)(ws + 16777216);
    unsigned short* Qg  = (unsigned short*)(dob);
    unsigned short* Kg  = (unsigned short*)(dob + 16777216);

    const bool have_xbf = (ws_size >= (size_t)50331648);
    unsigned short* Xbf = (unsigned short*)(ws + 33554432);

    // 1. QKV projection in 3 column-chunks: transpose chunk -> GEMM (+RoPE/split)
    if (have_xbf) {
        int n4 = M_ * D_ / 4;
        cast_bf16_kernel<<<dim3((n4 + 255) / 256), dim3(256), 0, stream>>>(hs, Xbf, n4);
        for (int c = 0; c < 3; c++) {
            transpose_cast_kernel<<<dim3(64, 64), dim3(256), 0, stream>>>(
                Wqkv + c*2048, TW, D_, N3_);
            gemm_bt2_kernel<1, 1><<<dim3(16, 32), dim3(512), 0, stream>>>(
                Xbf, TW, bqkv, Qg, Kg, Vt, N3_, D_, c*2048);
        }
    } else {
        for (int c = 0; c < 3; c++) {
            transpose_cast_kernel<<<dim3(64, 64), dim3(256), 0, stream>>>(
                Wqkv + c*2048, TW, D_, N3_);
            gemm_bt2_kernel<0, 1><<<dim3(16, 32), dim3(512), 0, stream>>>(
                hs, TW, bqkv, Qg, Kg, Vt, N3_, D_, c*2048);
        }
    }
    // 2. causal flash attention (verified softmax structure, swizzled grid)
    flash3_kernel<<<dim3(S_/64, B_*H_), dim3(256), 0, stream>>>(Qg, Kg, Vt, ctx);
    // 3. W_dense^T (Vt dead), then dense projection, fp32 out
    transpose_cast_kernel<<<dim3(64, 64), dim3(256), 0, stream>>>(
        Wd, WdT, D_, D_);
    gemm_bt2_kernel<1, 0><<<dim3(16, 32), dim3(512), 0, stream>>>(
        ctx, WdT, bd, out, nullptr, nullptr, D_, D_, 0);
}

// Round 6
// 380.539 us; speedup vs baseline: 1.6217x; 1.1154x over previous
//
#include <hip/hip_runtime.h>
#include <hip/hip_bf16.h>
#include <math.h>

#define B_   2
#define S_   2048
#define D_   2048
#define H_   16
#define HD_  128
#define ROT_ 32
#define M_   (B_*S_)    // 4096 tokens
#define N3_  (3*D_)     // 6144

static constexpr float SCALE_ = 0.08838834764831845f;  // 1/sqrt(128)

typedef __attribute__((ext_vector_type(4))) float  f32x4;
typedef __attribute__((ext_vector_type(8))) __bf16 bf16x8;

__device__ inline unsigned short f2bf(float f) {
    unsigned int u = __builtin_bit_cast(unsigned int, f);
    unsigned int r = (u + 0x7fffu + ((u >> 16) & 1u)) >> 16;
    return (unsigned short)r;
}
__device__ inline float bf2f(unsigned short h) {
    unsigned int u = ((unsigned int)h) << 16;
    return __builtin_bit_cast(float, u);
}

#define GLDS(g, l) __builtin_amdgcn_global_load_lds(                          \
    (const __attribute__((address_space(1))) void*)(g),                       \
    (__attribute__((address_space(3))) void*)(l), 16, 0, 0)

// ---------------------------------------------------------------- cast fp32 -> bf16
__global__ void cast_bf16_kernel(const float* __restrict__ src,
                                 unsigned short* __restrict__ dst, int n4) {
    int i = blockIdx.x * blockDim.x + threadIdx.x;
    if (i < n4) {
        float4 v = ((const float4*)src)[i];
        ushort4 o;
        o.x = f2bf(v.x); o.y = f2bf(v.y); o.z = f2bf(v.z); o.w = f2bf(v.w);
        ((ushort4*)dst)[i] = o;
    }
}

// ------------------------------------------- transpose+cast (conflict-free)
__global__ __launch_bounds__(256) void transpose_cast_kernel(
    const float* __restrict__ src, unsigned short* __restrict__ dst,
    int R, int ldS)
{
    __shared__ float tile[32][33];
    int c0 = blockIdx.x * 32, r0 = blockIdx.y * 32;
    int tx = threadIdx.x & 31, ty = threadIdx.x >> 5;  // ty 0..7
#pragma unroll
    for (int i = 0; i < 4; i++)
        tile[ty + i*8][tx] = src[(size_t)(r0 + ty + i*8) * ldS + c0 + tx];
    __syncthreads();
#pragma unroll
    for (int i = 0; i < 4; i++)
        dst[(size_t)(c0 + ty + i*8) * R + r0 + tx] = f2bf(tile[tx][ty + i*8]);
}

// ---------------------------------------------------------------- GEMM (B^T, GLDS both sides)
// r11: 8-wave, BK=64, T2 XOR-swizzled LDS tiles (both sides).
//   - BK=64 halves barrier crossings (16 MFMA/phase/wave instead of 8).
//   - Row stride becomes 128B -> would be a 16-way bank conflict on every
//     ds_read_b128; the flash-verified XOR swizzle (chunk ^= row&7, applied
//     as pre-swizzled GLDS *source* column + swizzled read) makes it 2-way
//     (free). LDS 32KB (grid-limited at 2 blocks/CU, so no occupancy cost).
// MODE 0: fp32 C (+bias). MODE 1: qkv epilogue (bias+RoPE+head-split scatter).
// Q (part==0) pre-scaled by 1/sqrt(HD) (commutes with RoPE; exact).
template <int ABF16, int MODE>
__global__ __launch_bounds__(512) void gemm_bt2_kernel(
    const void* __restrict__ Aptr,
    const unsigned short* __restrict__ BT,
    const float* __restrict__ bias,
    void* __restrict__ out0,
    unsigned short* __restrict__ out1,
    unsigned short* __restrict__ out2,
    int Ndim, int K, int n_base)
{
    __shared__ unsigned short sA[128 * 64];
    __shared__ unsigned short sB[128 * 64];
    const int tid  = threadIdx.x;
    // XCD-chunked swizzle: dispatch id d -> XCD d&7 (round-robin heuristic).
    // XCD x gets i = d>>3 in [0,64): by' = x*4 + (i>>4), bx' = i&15. Bijective.
    const int d    = (int)blockIdx.x + (int)blockIdx.y * (int)gridDim.x;
    const int xcd  = d & 7, ii = d >> 3;
    const int m0   = (xcd * 4 + (ii >> 4)) * 128;
    const int nloc = (ii & 15) * 128;
    const int n0   = n_base + nloc;
    const int lane = tid & 63, wave = tid >> 6;          // 8 waves
    const int wr = wave >> 1, wc = wave & 1;             // wr 0..3, wc 0..1
    const int lrow = lane & 15, quad = lane >> 4;
    const int sw = lrow & 7;                             // read-side swizzle key

    f32x4 acc[2][4] = {};

    // pre-swizzled source column (shorts): chunk' = (tid&7) ^ (row&7), row = tid/8 (mod 8)
    const int axcol = ((tid & 7) ^ ((tid >> 3) & 7)) * 8;
    const unsigned short* Bg = BT + (size_t)(nloc + tid/8) * K + axcol;

    for (int k0 = 0; k0 < K; k0 += 64) {
        if (ABF16) {
            const unsigned short* Ag = (const unsigned short*)Aptr
                                     + (size_t)(m0 + tid/8) * K + axcol;
#pragma unroll
            for (int p = 0; p < 2; p++)
                GLDS(Ag + (size_t)p*64*K + k0, sA + p*4096 + tid*8);
        } else {
            const float* Af = (const float*)Aptr;
#pragma unroll
            for (int p = 0; p < 4; p++) {
                int row = p*32 + tid/16, colv = (tid & 15) * 4;  // 4 fp32 elems
                float4 v = *(const float4*)&Af[(size_t)(m0 + row) * K + k0 + colv];
                ushort4 o;
                o.x = f2bf(v.x); o.y = f2bf(v.y); o.z = f2bf(v.z); o.w = f2bf(v.w);
                int ch = colv >> 3, off = colv & 7;
                *(ushort4*)&sA[row*64 + ((ch ^ (row & 7)) << 3) + off] = o;
            }
        }
#pragma unroll
        for (int p = 0; p < 2; p++)
            GLDS(Bg + (size_t)p*64*K + k0, sB + p*4096 + tid*8);
        __syncthreads();
        bf16x8 af[2][2], bfj[2][4];
#pragma unroll
        for (int kk = 0; kk < 2; kk++) {
            const int cix = ((kk*4 + quad) ^ sw) << 3;
#pragma unroll
            for (int i = 0; i < 2; i++)
                af[kk][i]  = *(const bf16x8*)&sA[(wr*32 + i*16 + lrow)*64 + cix];
#pragma unroll
            for (int j = 0; j < 4; j++)
                bfj[kk][j] = *(const bf16x8*)&sB[(wc*64 + j*16 + lrow)*64 + cix];
        }
#pragma unroll
        for (int kk = 0; kk < 2; kk++)
#pragma unroll
            for (int i = 0; i < 2; i++)
#pragma unroll
                for (int j = 0; j < 4; j++)
                    acc[i][j] = __builtin_amdgcn_mfma_f32_16x16x32_bf16(
                        af[kk][i], bfj[kk][j], acc[i][j], 0, 0, 0);
        __syncthreads();
    }

    if (MODE == 0) {
#pragma unroll
        for (int i = 0; i < 2; i++) {
#pragma unroll
            for (int j = 0; j < 4; j++) {
                int col = n0 + wc*64 + j*16 + lrow;
                float bv = bias[col];
#pragma unroll
                for (int r = 0; r < 4; r++) {
                    int row = m0 + wr*32 + i*16 + quad*4 + r;
                    ((float*)out0)[(size_t)row * Ndim + col] = acc[i][j][r] + bv;
                }
            }
        }
    } else {
        const int t = n0 >> 7, part = t % 3, h = t / 3;
        float bv[4];
#pragma unroll
        for (int j = 0; j < 4; j++)
            bv[j] = bias[n0 + wc*64 + j*16 + lrow];

#pragma unroll
        for (int i = 0; i < 2; i++) {
            const int rowb = m0 + wr*32 + i*16 + quad*4;
            const int b = rowb >> 11, sbase = rowb & 2047;
            if (part == 2) {
                size_t vb = ((size_t)(b*H_ + h)) * HD_ * S_;
#pragma unroll
                for (int j = 0; j < 4; j++) {
                    int dd = wc*64 + j*16 + lrow;
                    ushort4 o;
                    o.x = f2bf(acc[i][j][0] + bv[j]);
                    o.y = f2bf(acc[i][j][1] + bv[j]);
                    o.z = f2bf(acc[i][j][2] + bv[j]);
                    o.w = f2bf(acc[i][j][3] + bv[j]);
                    *(ushort4*)&out2[vb + (size_t)dd * S_ + sbase] = o;
                }
            } else {
                unsigned short* outp = (part == 0) ? (unsigned short*)out0 : out1;
                size_t qb = ((size_t)(b*H_ + h)) * S_ * HD_;
#pragma unroll
                for (int r = 0; r < 4; r++) {
                    int s = sbase + r;
                    float vals[4];
#pragma unroll
                    for (int j = 0; j < 4; j++)
                        vals[j] = acc[i][j][r] + bv[j];
                    if (part == 0) {
#pragma unroll
                        for (int j = 0; j < 4; j++)
                            vals[j] *= SCALE_;   // fold 1/sqrt(HD) into Q (exact)
                    }
                    if (wc == 0) {
                        float inv = exp2f(-(float)lrow * 0.8304817737218413f); // 10000^(-lrow/16)
                        float ang = (float)s * inv, sn, cs;
                        sincosf(ang, &sn, &cs);
                        float v0 = vals[0]*cs - vals[1]*sn;
                        float v1 = vals[1]*cs + vals[0]*sn;
                        vals[0] = v0; vals[1] = v1;
                    }
#pragma unroll
                    for (int j = 0; j < 4; j++)
                        outp[qb + (size_t)s * HD_ + wc*64 + j*16 + lrow] = f2bf(vals[j]);
                }
            }
        }
    }
}

// ---------------------------------------------------------------- flash attention v4c
// (verified R4, 90us) XCD-chunked grid, diagonal-only mask, pre-scaled Q,
// fence between softmax LDS writes and PV LDS reads. UNCHANGED this round.
__global__ __launch_bounds__(256) void flash3_kernel(
    const unsigned short* __restrict__ Qg,
    const unsigned short* __restrict__ Kg,
    const unsigned short* __restrict__ Vt,
    unsigned short* __restrict__ ctx)
{
    __shared__ unsigned short sK[64 * 128];   // K tile [key][d] (also Q staging), swizzled
    __shared__ unsigned short sVt[128 * 64];  // V^T tile [d][key], swizzled
    __shared__ float          sS[64 * 65];    // fp32 scores [q][k], padded
    __shared__ unsigned short sP[64 * 72];    // bf16 probs [q][k], padded
    __shared__ float sM[64], sL[64], sAl[64]; // per-row online-softmax state

    const int tid = threadIdx.x, lane = tid & 63, wave = tid >> 6;
    // XCD-chunked bijection: dispatch d -> xcd = d&7, i = d>>3 in [0,128):
    //   bh = xcd*4 + (i&3), q-tile index descends (heavy first).
    const int d   = (int)blockIdx.x + (int)blockIdx.y * (int)gridDim.x;
    const int xcd = d & 7, ii = d >> 3;
    const int bh  = xcd * 4 + (ii & 3);
    const int q0  = (31 - (ii >> 2)) * 64;
    const int b = bh / H_, h = bh % H_;
    const unsigned short* Qb = Qg + (size_t)bh * S_ * HD_;
    const unsigned short* Kb = Kg + (size_t)bh * S_ * HD_;
    const unsigned short* Vb = Vt + (size_t)bh * HD_ * S_;
    const int lrow = lane & 15, quad = lane >> 4, lk = quad * 8;
    const int sw = lrow & 7;                       // read-side swizzle key
    const int qkcol = ((tid & 15) ^ ((tid >> 4) & 7)) * 8;  // sK staging src col (shorts)
    const int vcol  = ((tid & 7)  ^ ((tid >> 3) & 7)) * 8;  // sVt staging src col (shorts)

    if (quad == 0) { sM[wave*16 + lrow] = -1e30f; sL[wave*16 + lrow] = 0.f; }

#pragma unroll
    for (int c = 0; c < 4; c++)
        GLDS(Qb + (size_t)(q0 + c*16 + tid/16) * HD_ + qkcol, sK + c*2048 + tid*8);
    __syncthreads();
    bf16x8 qf[4];
#pragma unroll
    for (int c = 0; c < 4; c++)
        qf[c] = *(const bf16x8*)&sK[(wave*16 + lrow)*128 + ((c*4 + quad) ^ sw)*8];
    __syncthreads();

    f32x4 O[8] = {};

    const int ktiles = (q0 >> 6) + 1;
    for (int kt = 0; kt < ktiles; kt++) {
        const int ks = kt * 64;
#pragma unroll
        for (int c = 0; c < 4; c++)
            GLDS(Kb + (size_t)(ks + c*16 + tid/16) * HD_ + qkcol, sK  + c*2048 + tid*8);
#pragma unroll
        for (int c = 0; c < 4; c++)
            GLDS(Vb + (size_t)(c*32 + tid/8) * S_ + ks + vcol,    sVt + c*2048 + tid*8);
        __syncthreads();   // sK/sVt ready (shared across waves)

        // S = Q K^T (Q pre-scaled); write to wave-private sS rows in plain [q][k]
        f32x4 sc[4] = {};
#pragma unroll
        for (int j = 0; j < 4; j++)
#pragma unroll
            for (int c = 0; c < 4; c++) {
                bf16x8 kf = *(const bf16x8*)&sK[(j*16 + lrow)*128 + ((c*4 + quad) ^ sw)*8];
                sc[j] = __builtin_amdgcn_mfma_f32_16x16x32_bf16(qf[c], kf, sc[j], 0, 0, 0);
            }
        if (kt == ktiles - 1) {
            // diagonal tile (ks == q0): mask kcol > qrow, block-local indices
#pragma unroll
            for (int j = 0; j < 4; j++) {
                const int kcol = j*16 + lrow;
#pragma unroll
                for (int r = 0; r < 4; r++) {
                    const int qrow = wave*16 + quad*4 + r;
                    sS[qrow*65 + kcol] = (kcol <= qrow) ? sc[j][r] : -1e30f;
                }
            }
        } else {
#pragma unroll
            for (int j = 0; j < 4; j++) {
                const int kcol = j*16 + lrow;
#pragma unroll
                for (int r = 0; r < 4; r++) {
                    const int qrow = wave*16 + quad*4 + r;
                    sS[qrow*65 + kcol] = sc[j][r];
                }
            }
        }

        // parallel online softmax: lane (quad,lrow) -> row lrow, cols quad*16..+15
        {
            const int row = wave*16 + lrow;
            const float* Sr = &sS[row*65 + quad*16];
            float tm = -1e30f;
#pragma unroll
            for (int c = 0; c < 16; c++) tm = fmaxf(tm, Sr[c]);
            tm = fmaxf(tm, __shfl_xor(tm, 16, 64));
            tm = fmaxf(tm, __shfl_xor(tm, 32, 64));
            float mprev = sM[row];
            float mn = fmaxf(mprev, tm);
            float alpha = __expf(mprev - mn);
            float sum = 0.f;
            unsigned short* Pr = &sP[row*72 + quad*16];
#pragma unroll
            for (int c4 = 0; c4 < 4; c4++) {
                ushort4 o;
                float p0 = __expf(Sr[c4*4+0] - mn);
                float p1 = __expf(Sr[c4*4+1] - mn);
                float p2 = __expf(Sr[c4*4+2] - mn);
                float p3 = __expf(Sr[c4*4+3] - mn);
                sum += p0 + p1 + p2 + p3;
                o.x = f2bf(p0); o.y = f2bf(p1); o.z = f2bf(p2); o.w = f2bf(p3);
                *(ushort4*)&Pr[c4*4] = o;
            }
            sum += __shfl_xor(sum, 16, 64);
            sum += __shfl_xor(sum, 32, 64);
            if (quad == 0) {
                sM[row] = mn;
                sL[row] = sL[row]*alpha + sum;
                sAl[row] = alpha;
            }
        }
        asm volatile("" ::: "memory");   // order softmax LDS writes before PV LDS reads

        // rescale O, then O += P V  (sP/sAl wave-private; wave-ordered LDS)
        float al[4];
#pragma unroll
        for (int r = 0; r < 4; r++) al[r] = sAl[wave*16 + quad*4 + r];
#pragma unroll
        for (int jo = 0; jo < 8; jo++)
#pragma unroll
            for (int r = 0; r < 4; r++) O[jo][r] *= al[r];
#pragma unroll
        for (int c = 0; c < 2; c++) {
            bf16x8 pf = *(const bf16x8*)&sP[(wave*16 + lrow)*72 + c*32 + lk];
#pragma unroll
            for (int jo = 0; jo < 8; jo++) {
                bf16x8 vf = *(const bf16x8*)&sVt[(jo*16 + lrow)*64 + ((c*4 + quad) ^ sw)*8];
                O[jo] = __builtin_amdgcn_mfma_f32_16x16x32_bf16(pf, vf, O[jo], 0, 0, 0);
            }
        }
        __syncthreads();   // all waves done with sK/sVt before next GLDS
    }

    float li[4];
#pragma unroll
    for (int r = 0; r < 4; r++) li[r] = sL[wave*16 + quad*4 + r];
#pragma unroll
    for (int jo = 0; jo < 8; jo++) {
        const int dcol = jo*16 + lrow;
#pragma unroll
        for (int r = 0; r < 4; r++) {
            const int srow = q0 + wave*16 + quad*4 + r;
            ctx[((size_t)b * S_ + srow) * D_ + h*HD_ + dcol] = f2bf(O[jo][r] / li[r]);
        }
    }
}

// ---------------------------------------------------------------- launch
extern "C" void kernel_launch(void* const* d_in, const int* in_sizes, int n_in,
                              void* d_out, int out_size, void* d_ws, size_t ws_size,
                              hipStream_t stream) {
    const float* hs   = (const float*)d_in[0];
    // d_in[1] attention_mask: all ones, unused by the reference math
    const float* Wqkv = (const float*)d_in[2];
    const float* bqkv = (const float*)d_in[3];
    const float* Wd   = (const float*)d_in[4];
    const float* bd   = (const float*)d_in[5];
    float* out = (float*)d_out;

    char* ws  = (char*)d_ws;
    char* dob = (char*)d_out;
    // Memory map (base footprint 32 MiB, verified r4-r6):
    //   ws[0,16MiB):   Vt [bh][d][s]; WdT at ws[0,8MiB) after flash.
    //   ws[16,24MiB):  TW (per-chunk W^T) during gemm1; ctx ws[16,32) after.
    //   ws[32,48MiB):  Xbf (optional, only if ws_size >= 48MiB).
    //   d_out[0,16):   Qg ; d_out[16,32): Kg (dead before gemm2 writes).
    unsigned short* Vt  = (unsigned short*)(ws);
    unsigned short* WdT = (unsigned short*)(ws);
    unsigned short* TW  = (unsigned short*)(ws + 16777216);
    unsigned short* ctx = (unsigned short*)(ws + 16777216);
    unsigned short* Qg  = (unsigned short*)(dob);
    unsigned short* Kg  = (unsigned short*)(dob + 16777216);

    const bool have_xbf = (ws_size >= (size_t)50331648);
    unsigned short* Xbf = (unsigned short*)(ws + 33554432);

    // 1. QKV projection in 3 column-chunks: transpose chunk -> GEMM (+RoPE/split)
    if (have_xbf) {
        int n4 = M_ * D_ / 4;
        cast_bf16_kernel<<<dim3((n4 + 255) / 256), dim3(256), 0, stream>>>(hs, Xbf, n4);
        for (int c = 0; c < 3; c++) {
            transpose_cast_kernel<<<dim3(64, 64), dim3(256), 0, stream>>>(
                Wqkv + c*2048, TW, D_, N3_);
            gemm_bt2_kernel<1, 1><<<dim3(16, 32), dim3(512), 0, stream>>>(
                Xbf, TW, bqkv, Qg, Kg, Vt, N3_, D_, c*2048);
        }
    } else {
        for (int c = 0; c < 3; c++) {
            transpose_cast_kernel<<<dim3(64, 64), dim3(256), 0, stream>>>(
                Wqkv + c*2048, TW, D_, N3_);
            gemm_bt2_kernel<0, 1><<<dim3(16, 32), dim3(512), 0, stream>>>(
                hs, TW, bqkv, Qg, Kg, Vt, N3_, D_, c*2048);
        }
    }
    // 2. causal flash attention (verified softmax structure, swizzled grid)
    flash3_kernel<<<dim3(S_/64, B_*H_), dim3(256), 0, stream>>>(Qg, Kg, Vt, ctx);
    // 3. W_dense^T (Vt dead), then dense projection, fp32 out
    transpose_cast_kernel<<<dim3(64, 64), dim3(256), 0, stream>>>(
        Wd, WdT, D_, D_);
    gemm_bt2_kernel<1, 0><<<dim3(16, 32), dim3(512), 0, stream>>>(
        ctx, WdT, bd, out, nullptr, nullptr, D_, D_, 0);
}